// Round 9
// baseline (43.255 us; speedup 1.0000x reference)
//
#include <hip/hip_runtime.h>
#include <hip/hip_bf16.h>
#include <cstdint>
#include <cstddef>

typedef short bf16x8 __attribute__((ext_vector_type(8)));
typedef float f32x4 __attribute__((ext_vector_type(4)));

#define BN 8
#define TN 2048
#define CN 1024
#define HN 64

__device__ __forceinline__ unsigned short f2bf(float f) {
    unsigned int u = __float_as_uint(f);
    u += 0x7fffu + ((u >> 16) & 1u);
    return (unsigned short)(u >> 16);
}

// packed f32x2 -> bf16x2 (v_cvt_pk_bf16_f32), lo in low half
__device__ __forceinline__ int pk2(float lo, float hi) {
    float2 t; t.x = lo; t.y = hi;
    __hip_bfloat162 h = __float22bfloat162_rn(t);
    return *reinterpret_cast<int*>(&h);
}

// async global->LDS copy, 16 B per lane; ldst must be the WAVE-UNIFORM base
// (HW adds lane*16), gsrc is per-lane.
__device__ __forceinline__ void gload_lds16(const unsigned short* gsrc, void* ldst) {
    __builtin_amdgcn_global_load_lds(
        (const __attribute__((address_space(1))) unsigned int*)gsrc,
        (__attribute__((address_space(3))) unsigned int*)ldst,
        16, 0, 0);
}

// Build Wp: W in MFMA-B-fragment-packed order.
// Logical Wct[n][c], n in [0,192): n<64 = Wq col h (pre-scaled by 0.125*log2e),
// 64..127 = Wk, 128..191 = Wv.  Fragment (tile=n>>4, kk=c>>5): lane = lg*16+lq
// (lg=(c>>3)&3, lq=n&15), elem e=c&7.
// idx = ((tile*32+kk)*64 + lg*16 + lq)*8 + e  -> wave loads are lane-contiguous.
__global__ __launch_bounds__(256) void wconv_kernel(const float* __restrict__ Wq,
                                                    const float* __restrict__ Wk,
                                                    const float* __restrict__ Wv,
                                                    unsigned short* __restrict__ Wp) {
    int idx = blockIdx.x * 256 + threadIdx.x;   // 0..196607
    int n = idx >> 10;
    int c = idx & 1023;
    int m = n >> 6;
    int h = n & 63;
    const float* W = (m == 0) ? Wq : ((m == 1) ? Wk : Wv);
    float v = W[c * 64 + h];
    if (m == 0) v *= 0.18033688011112042f;  // (1/sqrt(64)) * log2(e)
    const int tile = n >> 4, lq = n & 15;
    const int kk = c >> 5, lg = (c >> 3) & 3, e = c & 7;
    Wp[(size_t)(((tile * 32 + kk) * 64 + lg * 16 + lq) * 8 + e)] = f2bf(v);
}

// Fused QKV projection v9: BM=64, BN=96, BK=64; 512 blocks (256 M x 2 N-half)
// x 512 threads (8 waves: 4 M-tiles x 2 N-subhalves).  40 KB LDS (2-3 blk/CU).
// W staged async via global_load_lds; X reg-staged fp32->bf16 (packed cvt).
// nh = bid>>8 so the two blocks sharing an X tile land on the same XCD.
__global__ __launch_bounds__(512) void proj_kernel(const float* __restrict__ X,
                                                   const unsigned short* __restrict__ Wp,
                                                   unsigned short* __restrict__ Qs,
                                                   unsigned short* __restrict__ Kp,
                                                   unsigned short* __restrict__ Vp) {
    __shared__ short Xs[2][64 * 64];     // 2 x 8 KB bf16
    __shared__ short Wsh[2][6144];       // 2 x 12 KB bf16

    const int tid = threadIdx.x;
    const int w   = tid >> 6;       // 0..7
    const int l   = tid & 63;
    const int lq  = l & 15;
    const int lg  = l >> 4;
    const int mr   = w >> 1;        // M-tile 0..3
    const int nsub = w & 1;         // N-subhalf 0..1
    const int bid = blockIdx.x;
    const int mtile = bid & 255;
    const int nh    = bid >> 8;     // N-half 0..1
    const int rowbase = mtile * 64;

    // --- X staging addresses (per thread): 64 rows x 64 cols fp32 ---
    const int xrow = tid >> 3;             // 0..63
    const int xcol = (tid & 7) * 8;        // 0..56 (floats)
    const float* xsrc = X + (size_t)(rowbase + xrow) * CN + xcol;
    const int xdst = xrow * 128 + (((xcol * 2)) ^ ((xrow & 7) << 4));  // byte

    // --- W staging: 6 tiles x BK=64 = 6144 elems/step = 12288 B ---
    // round0: all 512 threads (elems 0..4095), round1: tid<256 (4096..6143)
    const unsigned short* wsrc0 = Wp + (size_t)((nh * 6 + (w >> 1)) * 32 + (w & 1)) * 512 + l * 8;
    const int wdstb0 = (w * 512) * 2;                 // wave-uniform byte base
    const unsigned short* wsrc1 = Wp + (size_t)((nh * 6 + 4 + (w >> 1)) * 32 + (w & 1)) * 512 + l * 8;
    const int wdstb1 = (4096 + w * 512) * 2;

    // --- compute-side LDS addresses (per lane) ---
    const int arow = mr * 16 + lq;
    int aaddr[2];
    #pragma unroll
    for (int kkL = 0; kkL < 2; ++kkL)
        aaddr[kkL] = arow * 128 + (((kkL * 64 + lg * 16)) ^ ((arow & 7) << 4));
    int baddr[2][3];
    #pragma unroll
    for (int kkL = 0; kkL < 2; ++kkL)
        #pragma unroll
        for (int jj = 0; jj < 3; ++jj)
            baddr[kkL][jj] = (((nsub * 3 + jj) * 2 + kkL) * 512 + l * 8) * 2;  // byte

    const f32x4 zero4 = {0.f, 0.f, 0.f, 0.f};
    f32x4 acc[3] = {zero4, zero4, zero4};

    // --- prologue: stage step 0 into buffer 0 ---
    {
        gload_lds16(wsrc0, (char*)Wsh[0] + wdstb0);
        if (tid < 256) gload_lds16(wsrc1, (char*)Wsh[0] + wdstb1);
        float4 xa = *(const float4*)(xsrc);
        float4 xb = *(const float4*)(xsrc + 4);
        int4 xc;
        xc.x = pk2(xa.x, xa.y); xc.y = pk2(xa.z, xa.w);
        xc.z = pk2(xb.x, xb.y); xc.w = pk2(xb.z, xb.w);
        *(int4*)((char*)Xs[0] + xdst) = xc;
        __syncthreads();
    }

    for (int s = 0; s < 16; ++s) {
        const int cur = s & 1;
        const int nxt = cur ^ 1;
        const bool more = (s + 1) < 16;
        // 1) issue next step's loads BEFORE compute (X first: longest latency)
        float4 xa, xb;
        if (more) {
            xa = *(const float4*)(xsrc + (s + 1) * 64);
            xb = *(const float4*)(xsrc + (s + 1) * 64 + 4);
            gload_lds16(wsrc0 + (s + 1) * 1024, (char*)Wsh[nxt] + wdstb0);
            if (tid < 256) gload_lds16(wsrc1 + (s + 1) * 1024, (char*)Wsh[nxt] + wdstb1);
        }
        // 2) compute current buffer: 12 MFMA
        #pragma unroll
        for (int kkL = 0; kkL < 2; ++kkL) {
            bf16x8 a  = *(const bf16x8*)((char*)Xs[cur] + aaddr[kkL]);
            bf16x8 b0 = *(const bf16x8*)((char*)Wsh[cur] + baddr[kkL][0]);
            bf16x8 b1 = *(const bf16x8*)((char*)Wsh[cur] + baddr[kkL][1]);
            bf16x8 b2 = *(const bf16x8*)((char*)Wsh[cur] + baddr[kkL][2]);
            acc[0] = __builtin_amdgcn_mfma_f32_16x16x32_bf16(a, b0, acc[0], 0, 0, 0);
            acc[1] = __builtin_amdgcn_mfma_f32_16x16x32_bf16(a, b1, acc[1], 0, 0, 0);
            acc[2] = __builtin_amdgcn_mfma_f32_16x16x32_bf16(a, b2, acc[2], 0, 0, 0);
        }
        // 3) convert + write next X buffer
        if (more) {
            int4 xc;
            xc.x = pk2(xa.x, xa.y); xc.y = pk2(xa.z, xa.w);
            xc.z = pk2(xb.x, xb.y); xc.w = pk2(xb.z, xb.w);
            *(int4*)((char*)Xs[nxt] + xdst) = xc;
        }
        // 4) one barrier per K-step (drains async W copies + X writes)
        __syncthreads();
    }

    // D layout: col = lane&15 (W col), row = 4*(lane>>4) + reg (X row)
    #pragma unroll
    for (int jj = 0; jj < 3; ++jj) {
        const int col = nh * 96 + nsub * 48 + jj * 16 + lq;
        const int mtx = col >> 6;          // 0=Q, 1=K, 2=V
        const int h   = col & 63;
        #pragma unroll
        for (int i = 0; i < 4; ++i) {
            const int g = rowbase + mr * 16 + 4 * lg + i;   // global token row
            const unsigned short val = f2bf(acc[jj][i]);
            const int b = g >> 11, tloc = g & 2047;
            const int kt = tloc >> 5;
            if (mtx == 0) {
                Qs[(size_t)g * 64 + h] = val;
            } else if (mtx == 1) {
                // K fragment-packed: frag = fa*2+ks, lane = lgk*16+lqk, elem e
                const int fa = (tloc >> 4) & 1, lqk = tloc & 15;
                const int ks = h >> 5, lgk = (h >> 3) & 3, e = h & 7;
                Kp[(size_t)(b * 64 + kt) * 2048 + (fa * 2 + ks) * 512 +
                   (lgk * 16 + lqk) * 8 + e] = val;
            } else {
                // V fragment-packed: frag = nf, lane = lgv*16+lqv, elem e
                const int tt = tloc & 31;
                const int lgv = (tt & 15) >> 2;
                const int e = (tt < 16) ? (tt & 3) : 4 + (tt & 3);
                const int nf = h >> 4, lqv = h & 15;
                Vp[(size_t)(b * 64 + kt) * 2048 + nf * 512 +
                   (lgv * 16 + lqv) * 8 + e] = val;
            }
        }
    }
}

// Block-cooperative causal flash attention, fragment-packed K/V.
// Block = (qt, b): 1024 blocks x 4 waves; heavy q-tiles launch first.
// Waves split the q-tile's key-tiles round-robin; partials merged in LDS.
// S^T = mfma(K, Q): lane&15 = query, key = 16*fa + 4*(lane>>4) + reg.
__global__ __launch_bounds__(256) void attn_kernel(const unsigned short* __restrict__ Qs,
                                                   const unsigned short* __restrict__ Kp,
                                                   const unsigned short* __restrict__ Vp,
                                                   float* __restrict__ Out) {
    __shared__ float lm[4][16];
    __shared__ float ll[4][16];
    __shared__ float facc[4][1024];

    const int tid = threadIdx.x;
    const int w  = tid >> 6;
    const int l  = tid & 63;
    const int lq = l & 15;
    const int lg = l >> 4;
    const int bid = blockIdx.x;
    const int qt = 127 - (bid >> 3);   // heavy first
    const int b  = bid & 7;
    const int q0 = qt * 16;
    const int nt = (qt >> 1) + 1;

    const unsigned short* Qb = Qs + (size_t)b * TN * 64;
    const unsigned short* KVbase_k = Kp + (size_t)b * 64 * 2048 + (size_t)l * 8;
    const unsigned short* KVbase_v = Vp + (size_t)b * 64 * 2048 + (size_t)l * 8;

    const f32x4 zero4 = {0.f, 0.f, 0.f, 0.f};

    bf16x8 qa0 = *(const bf16x8*)(Qb + (size_t)(q0 + lq) * 64 + lg * 8);
    bf16x8 qa1 = *(const bf16x8*)(Qb + (size_t)(q0 + lq) * 64 + 32 + lg * 8);

    f32x4 acc[4] = {zero4, zero4, zero4, zero4};
    float mrow = -1e30f;
    float lrow = 0.f;

    bf16x8 Kc[4], Vc[4], Kn[4], Vn[4];
    int kt = w;
    if (kt < nt) {
        const size_t tb = (size_t)kt * 2048;
        #pragma unroll
        for (int i = 0; i < 4; ++i) {
            Kc[i] = *(const bf16x8*)(KVbase_k + tb + i * 512);
            Vc[i] = *(const bf16x8*)(KVbase_v + tb + i * 512);
        }
    }

    for (; kt < nt; kt += 4) {
        const int ktn = kt + 4;
        if (ktn < nt) {   // prefetch next tile (coalesced 1KB loads)
            const size_t tb = (size_t)ktn * 2048;
            #pragma unroll
            for (int i = 0; i < 4; ++i) {
                Kn[i] = *(const bf16x8*)(KVbase_k + tb + i * 512);
                Vn[i] = *(const bf16x8*)(KVbase_v + tb + i * 512);
            }
        }

        const int key0 = kt * 32;
        f32x4 s[2];
        s[0] = __builtin_amdgcn_mfma_f32_16x16x32_bf16(Kc[0], qa0, zero4, 0, 0, 0);
        s[0] = __builtin_amdgcn_mfma_f32_16x16x32_bf16(Kc[1], qa1, s[0], 0, 0, 0);
        s[1] = __builtin_amdgcn_mfma_f32_16x16x32_bf16(Kc[2], qa0, zero4, 0, 0, 0);
        s[1] = __builtin_amdgcn_mfma_f32_16x16x32_bf16(Kc[3], qa1, s[1], 0, 0, 0);

        if (kt == nt - 1) {   // only the diagonal tile needs masking
            const int q = q0 + lq;
            #pragma unroll
            for (int fa = 0; fa < 2; ++fa)
                #pragma unroll
                for (int r = 0; r < 4; ++r) {
                    const int key = key0 + fa * 16 + 4 * lg + r;
                    if (key > q) s[fa][r] = -1e30f;
                }
        }

        float m1 = fmaxf(fmaxf(s[0][0], s[0][1]), s[0][2]);
        float m2 = fmaxf(fmaxf(s[0][3], s[1][0]), s[1][1]);
        float m3 = fmaxf(fmaxf(s[1][2], s[1][3]), m1);
        float tm = fmaxf(m2, m3);
        tm = fmaxf(tm, __shfl_xor(tm, 16));
        tm = fmaxf(tm, __shfl_xor(tm, 32));

        // defer-max: only rescale when max grows by > 8 (P bounded by 2^8)
        if (!__all(tm <= mrow + 8.0f)) {
            const float mnew = fmaxf(mrow, tm);
            const float cc = __builtin_amdgcn_exp2f(mrow - mnew);
            lrow *= cc;
            float cb[4];
            #pragma unroll
            for (int i = 0; i < 4; ++i) cb[i] = __shfl(cc, 4 * lg + i);
            #pragma unroll
            for (int nf = 0; nf < 4; ++nf)
                #pragma unroll
                for (int i = 0; i < 4; ++i) acc[nf][i] *= cb[i];
            mrow = mnew;
        }

        float p[2][4];
        float psum = 0.f;
        #pragma unroll
        for (int fa = 0; fa < 2; ++fa)
            #pragma unroll
            for (int r = 0; r < 4; ++r) {
                p[fa][r] = __builtin_amdgcn_exp2f(s[fa][r] - mrow);
                psum += p[fa][r];
            }
        psum += __shfl_xor(psum, 16);
        psum += __shfl_xor(psum, 32);
        lrow += psum;

        bf16x8 pa;
        pa[0] = (short)f2bf(p[0][0]); pa[1] = (short)f2bf(p[0][1]);
        pa[2] = (short)f2bf(p[0][2]); pa[3] = (short)f2bf(p[0][3]);
        pa[4] = (short)f2bf(p[1][0]); pa[5] = (short)f2bf(p[1][1]);
        pa[6] = (short)f2bf(p[1][2]); pa[7] = (short)f2bf(p[1][3]);

        acc[0] = __builtin_amdgcn_mfma_f32_16x16x32_bf16(pa, Vc[0], acc[0], 0, 0, 0);
        acc[1] = __builtin_amdgcn_mfma_f32_16x16x32_bf16(pa, Vc[1], acc[1], 0, 0, 0);
        acc[2] = __builtin_amdgcn_mfma_f32_16x16x32_bf16(pa, Vc[2], acc[2], 0, 0, 0);
        acc[3] = __builtin_amdgcn_mfma_f32_16x16x32_bf16(pa, Vc[3], acc[3], 0, 0, 0);

        #pragma unroll
        for (int i = 0; i < 4; ++i) { Kc[i] = Kn[i]; Vc[i] = Vn[i]; }
    }

    // store partial state to LDS
    if (lg == 0) {
        lm[w][lq] = mrow;
        ll[w][lq] = lrow;
    }
    #pragma unroll
    for (int nf = 0; nf < 4; ++nf)
        #pragma unroll
        for (int i = 0; i < 4; ++i)
            facc[w][(4 * lg + i) * 64 + nf * 16 + lq] = acc[nf][i];

    __syncthreads();

    // merge 4 wave-partials and write Out
    #pragma unroll
    for (int ii = 0; ii < 4; ++ii) {
        const int e = tid + ii * 256;
        const int q = e >> 6;
        const int h = e & 63;
        const float M = fmaxf(fmaxf(lm[0][q], lm[1][q]),
                              fmaxf(lm[2][q], lm[3][q]));
        float L = 0.f, O = 0.f;
        #pragma unroll
        for (int c = 0; c < 4; ++c) {
            const float wgt = __builtin_amdgcn_exp2f(lm[c][q] - M);
            L += wgt * ll[c][q];
            O += wgt * facc[c][q * 64 + h];
        }
        Out[((size_t)b * TN + q0 + q) * 64 + h] = O / L;
    }
}

extern "C" void kernel_launch(void* const* d_in, const int* in_sizes, int n_in,
                              void* d_out, int out_size, void* d_ws, size_t ws_size,
                              hipStream_t stream) {
    const float* X  = (const float*)d_in[0];
    const float* Wq = (const float*)d_in[1];
    const float* Wk = (const float*)d_in[2];
    const float* Wv = (const float*)d_in[3];
    float* Out = (float*)d_out;

    char* ws = (char*)d_ws;
    unsigned short* Wp = (unsigned short*)(ws);                 // 384 KB (pad 512 KB)
    unsigned short* Qs = (unsigned short*)(ws + (512u << 10));  // 2 MB
    unsigned short* Kp = Qs + (size_t)16384 * 64;               // 2 MB
    unsigned short* Vp = Kp + (size_t)16384 * 64;               // 2 MB

    hipLaunchKernelGGL(wconv_kernel, dim3(768), dim3(256), 0, stream, Wq, Wk, Wv, Wp);
    hipLaunchKernelGGL(proj_kernel,  dim3(512), dim3(512), 0, stream, X, Wp, Qs, Kp, Vp);
    hipLaunchKernelGGL(attn_kernel,  dim3(1024), dim3(256), 0, stream, Qs, Kp, Vp, Out);
}